// Round 9
// baseline (560.259 us; speedup 1.0000x reference)
//
#include <hip/hip_runtime.h>

#define HID 4096
#define QKVDIM 12288
#define SEQ 2048
#define SCALE 0.0625f

typedef unsigned short u16;
typedef unsigned int u32;
typedef __attribute__((ext_vector_type(8))) short short8;   // 8 x bf16 (4 VGPR)
typedef __attribute__((ext_vector_type(4))) float f32x4;
typedef __attribute__((ext_vector_type(4))) unsigned int u32x4;
typedef __attribute__((ext_vector_type(4))) float float4v;

__device__ __forceinline__ u16 f2bf(float f) {
  union { float f; u32 u; } v; v.f = f;
  return (u16)((v.u + 0x7fffu + ((v.u >> 16) & 1u)) >> 16);  // RNE
}
__device__ __forceinline__ float bf2f(u16 h) {
  union { u32 u; float f; } v; v.u = ((u32)h) << 16;
  return v.f;
}
__device__ __forceinline__ u32 pk2(float a, float b) {
  return (u32)f2bf(a) | ((u32)f2bf(b) << 16);
}

// ---------------------------------------------------------------------------
// fp32 -> bf16 bulk convert (8 elems/thread, grid-stride)
// ---------------------------------------------------------------------------
__global__ __launch_bounds__(256)
void conv_kernel(const float* __restrict__ in, u16* __restrict__ out, int n8) {
  for (int i = blockIdx.x * 256 + threadIdx.x; i < n8; i += gridDim.x * 256) {
    const float* p = in + (size_t)i * 8;
    float4v f0 = *(const float4v*)p;
    float4v f1 = *(const float4v*)(p + 4);
    u32x4 pk = (u32x4){pk2(f0.x, f0.y), pk2(f0.z, f0.w), pk2(f1.x, f1.y), pk2(f1.z, f1.w)};
    *(u32x4*)(out + (size_t)i * 8) = pk;
  }
}

// ---------------------------------------------------------------------------
// PIPELINED GEMM (T3+T4, round-7 proven): 256 x BROWS tile, BK=64, 8 waves,
// ring of 4 K-half slots per matrix. BROWS = 256 or 128.
// Per phase: [vmcnt(N); s_barrier] -> ds_read -> stage one A+B K-half
// (2 tiles ahead) -> lgkmcnt(0); sched_barrier -> setprio(1); MFMA cluster.
// CMODE: 0 = fp32 C; 1 = bf16 C into qkv q/k tiles; 2 = bf16 C^T into vT.
// ---------------------------------------------------------------------------
template <int CMODE, int BROWS>
__global__ __launch_bounds__(512)
void gemm_pipe(const u16* __restrict__ A, const u16* __restrict__ B,
               void* __restrict__ Cv, int K, int lda, int ldb, int ldc) {
  constexpr int NI = BROWS / 64;   // B sub-tiles per wave (4 or 2)
  constexpr int BI = BROWS / 128;  // B stage iterations (2 or 1)
  __shared__ __align__(16) u16 Asl[4][256 * 32];
  __shared__ __align__(16) u16 Bsl[4][BROWS * 32];
  const int t = threadIdx.x;  // 0..511
  const int w = t >> 6, lane = t & 63, g = lane >> 4, c = lane & 15;
  const int wm = w >> 2, wn = w & 3;

  // T1 XCD-aware swizzle (nwg % 8 == 0 in all launches)
  const int gx = gridDim.x;
  const int nwg = gx * gridDim.y;
  const int orig = blockIdx.y * gx + blockIdx.x;
  const int swz = (orig & 7) * (nwg >> 3) + (orig >> 3);
  const int bx = swz % gx, by = swz / gx;

  const int m0 = by * 256;
  int n0, vrow0 = 0;
  if (CMODE == 0) {
    n0 = bx * BROWS;
  } else if (CMODE == 1) {  // q/k tiles (BROWS=256): bx 0..31
    const int mp = bx >> 2, rr = bx & 3;
    n0 = mp * 1536 + (rr < 2 ? rr * 256 : 1024 + (rr - 2) * 256);
  } else {                  // v tiles (BROWS=128): bx 0..31
    const int mp = bx >> 2, rr = bx & 3;
    n0 = mp * 1536 + 512 + rr * 128;
    vrow0 = mp * 512 + rr * 128;
  }

  const int rowL = t >> 2;
  const int cSrc = ((t & 3) ^ ((t >> 2) & 3)) * 8;
  const u16* Asrc = A + (size_t)(m0 + rowL) * lda + cSrc;
  const u16* Bsrc = B + (size_t)(n0 + rowL) * ldb + cSrc;

  f32x4 acc[8][NI] = {};

#define STAGEH(slot, kcol)                                                     \
  {                                                                            \
    _Pragma("unroll") for (int i = 0; i < 2; ++i)                              \
        __builtin_amdgcn_global_load_lds(                                      \
            (const __attribute__((address_space(1))) u32*)(Asrc + (kcol) +     \
                                                           (size_t)(i * 128) * lda), \
            (__attribute__((address_space(3))) u32*)&Asl[slot][(i * 512 + w * 64) * 8], \
            16, 0, 0);                                                         \
    _Pragma("unroll") for (int i = 0; i < BI; ++i)                             \
        __builtin_amdgcn_global_load_lds(                                      \
            (const __attribute__((address_space(1))) u32*)(Bsrc + (kcol) +     \
                                                           (size_t)(i * 128) * ldb), \
            (__attribute__((address_space(3))) u32*)&Bsl[slot][(i * 512 + w * 64) * 8], \
            16, 0, 0);                                                         \
  }

  // prologue: Kh0(0), Kh1(0), Kh0(1)
  STAGEH(0, 0)
  STAGEH(1, 32)
  STAGEH(2, 64)

  const int NT = K >> 6;
  for (int j = 0; j < NT; ++j) {
    const int s0 = (2 * j) & 3;
#pragma unroll
    for (int h = 0; h < 2; ++h) {
      if (j + 1 < NT) {
        if (BROWS == 256)
          asm volatile("s_waitcnt vmcnt(8)\ns_barrier" ::: "memory");
        else
          asm volatile("s_waitcnt vmcnt(6)\ns_barrier" ::: "memory");
      } else if (h == 0) {
        if (BROWS == 256)
          asm volatile("s_waitcnt vmcnt(4)\ns_barrier" ::: "memory");
        else
          asm volatile("s_waitcnt vmcnt(3)\ns_barrier" ::: "memory");
      } else {
        asm volatile("s_waitcnt vmcnt(0)\ns_barrier" ::: "memory");
      }

      const u16* As = &Asl[(s0 + h) & 3][0];
      const u16* Bs = &Bsl[(s0 + h) & 3][0];
      short8 af[8], bf[NI];
#pragma unroll
      for (int mi = 0; mi < 8; ++mi) {
        const int row = wm * 128 + mi * 16 + c;
        af[mi] = *(const short8*)&As[(row * 32 + g * 8) ^ ((c & 3) << 3)];
      }
#pragma unroll
      for (int ni = 0; ni < NI; ++ni) {
        const int row = wn * (BROWS / 4) + ni * 16 + c;
        bf[ni] = *(const short8*)&Bs[(row * 32 + g * 8) ^ ((c & 3) << 3)];
      }
      if (h == 0) {
        if (j + 1 < NT) STAGEH((s0 + 3) & 3, (j + 1) * 64 + 32)
      } else {
        if (j + 2 < NT) STAGEH(s0, (j + 2) * 64)
      }

      asm volatile("s_waitcnt lgkmcnt(0)" ::: "memory");
      __builtin_amdgcn_sched_barrier(0);  // rule 18
      __builtin_amdgcn_s_setprio(1);
#pragma unroll
      for (int mi = 0; mi < 8; ++mi)
#pragma unroll
        for (int ni = 0; ni < NI; ++ni)
          acc[mi][ni] = (CMODE == 2)
              ? __builtin_amdgcn_mfma_f32_16x16x32_bf16(bf[ni], af[mi], acc[mi][ni], 0, 0, 0)
              : __builtin_amdgcn_mfma_f32_16x16x32_bf16(af[mi], bf[ni], acc[mi][ni], 0, 0, 0);
      __builtin_amdgcn_s_setprio(0);
      __builtin_amdgcn_sched_barrier(0);  // pin MFMA inside the phase
    }
  }
#undef STAGEH

  // epilogue. C/D layout: col = lane&15, row = (lane>>4)*4 + reg  [m89/m91]
#pragma unroll
  for (int mi = 0; mi < 8; ++mi)
#pragma unroll
    for (int ni = 0; ni < NI; ++ni)
#pragma unroll
      for (int r = 0; r < 4; ++r) {
        if (CMODE == 2) {
          const int vr = vrow0 + wn * (BROWS / 4) + ni * 16 + g * 4 + r;
          const int sc = m0 + wm * 128 + mi * 16 + c;
          ((u16*)Cv)[(size_t)vr * ldc + sc] = f2bf(acc[mi][ni][r]);
        } else {
          const int row = m0 + wm * 128 + mi * 16 + g * 4 + r;
          const int col = n0 + wn * (BROWS / 4) + ni * 16 + c;
          if (CMODE == 1)
            ((u16*)Cv)[(size_t)row * ldc + col] = f2bf(acc[mi][ni][r]);
          else
            ((float*)Cv)[(size_t)row * ldc + col] = acc[mi][ni][r];
        }
      }
}

// ---------------------------------------------------------------------------
// RoPE (GPT-J interleaved) in-place on q and k sections of qkv (bf16).
// ---------------------------------------------------------------------------
__global__ __launch_bounds__(256)
void rope_kernel(u16* __restrict__ qkv, const int* __restrict__ pos32) {
  const int idx = blockIdx.x * 256 + threadIdx.x;
  const int s = idx >> 9;
  const int rem = idx & 511;
  const int h = rem >> 5, i = rem & 31;
  const bool is64 = (pos32[1] == 0);
  const int pv = is64 ? pos32[2 * s] : pos32[s];
  const float pos = (float)pv;
  const float inv_freq = expf(-(float)i * (9.210340371976184f / 32.0f));
  const float f = pos * inv_freq;
  const float cs = cosf(f), sn = sinf(f);
  u16* p = qkv + (size_t)s * QKVDIM + (h >> 1) * 1536 + (h & 1) * 256 + 2 * i;
  {
    float x1 = bf2f(p[0]), x2 = bf2f(p[1]);
    p[0] = f2bf(x1 * cs - x2 * sn);
    p[1] = f2bf(x2 * cs + x1 * sn);
  }
  {
    u16* pk_ = p + 1024;
    float x1 = bf2f(pk_[0]), x2 = bf2f(pk_[1]);
    pk_[0] = f2bf(x1 * cs - x2 * sn);
    pk_[1] = f2bf(x2 * cs + x1 * sn);
  }
}

// ---------------------------------------------------------------------------
// Flash attention, causal. Grid (8 pairs, 16 heads); 8 waves; block owns a
// 128-q-row block per pass (waves 0..7 -> 16 rows each), K/V staged once per
// 128 rows. Pass 0: q-block bx (0..7); pass 1: 15-bx (8..15) -> each of the
// 16 q-blocks computed EXACTLY ONCE, uniform 68 KV-tiles per block.
// T14 async-stage, T13 defer-rescale (THR=8), T5 setprio.
// ---------------------------------------------------------------------------
__global__ __launch_bounds__(512)
void attn_kernel(const u16* __restrict__ qkv, const u16* __restrict__ vT,
                 u16* __restrict__ attnout) {
  __shared__ u16 Kl[32 * 256];
  __shared__ u16 Vl[256 * 40];
  __shared__ u16 Pl[8][16 * 40];

  const int t = threadIdx.x;                 // 0..511
  const int w = t >> 6, lane = t & 63, g = lane >> 4, c = lane & 15;
  const int head = blockIdx.y;
  const int q_off = (head >> 1) * 1536 + (head & 1) * 256;
  const int k_off = q_off + 1024;
  const u16* vTh = vT + (size_t)(head * 256) * SEQ;

  // staging maps: 1024 16B-chunks per matrix, 2 per thread (i = 0,1)
  const int kv0c = t >> 5, kv1c = (512 + t) >> 5;
  const int seg0 = (t & 31) ^ (kv0c & 7);
  const int seg1 = (t & 31) ^ (kv1c & 7);
  const int dV = t >> 2, q8V = (t & 3) * 8;

  for (int pass = 0; pass < 2; ++pass) {
    const int qb = pass ? (15 - (int)blockIdx.x) : (int)blockIdx.x;
    const int qrow = qb * 128 + w * 16;
    const int nt = 4 * qb + 4;

    short8 qf[8];
    {
      const u16* qbp = qkv + (size_t)(qrow + c) * QKVDIM + q_off + g * 8;
#pragma unroll
      for (int cc = 0; cc < 8; ++cc) qf[cc] = *(const short8*)(qbp + cc * 32);
    }

    f32x4 o[16] = {};
    float mrow[4], lrow[4];
#pragma unroll
    for (int r = 0; r < 4; ++r) { mrow[r] = -3.0e38f; lrow[r] = 0.0f; }

    u32x4 kreg[2], vreg[2];
    kreg[0] = *(const u32x4*)(qkv + (size_t)kv0c * QKVDIM + k_off + seg0 * 8);
    kreg[1] = *(const u32x4*)(qkv + (size_t)kv1c * QKVDIM + k_off + seg1 * 8);
    vreg[0] = *(const u32x4*)(vTh + (size_t)dV * SEQ + q8V);
    vreg[1] = *(const u32x4*)(vTh + (size_t)(dV + 128) * SEQ + q8V);
    __syncthreads();  // previous pass readers done before overwrite
    *(u32x4*)&Kl[t * 8] = kreg[0];
    *(u32x4*)&Kl[(512 + t) * 8] = kreg[1];
    *(u32x4*)&Vl[dV * 40 + q8V] = vreg[0];
    *(u32x4*)&Vl[(dV + 128) * 40 + q8V] = vreg[1];

    for (int ti = 0; ti < nt; ++ti) {
      __syncthreads();  // staged tile ti visible
      const int kv0 = ti * 32;
      const bool more = (ti + 1 < nt);
      if (more) {  // T14: issue next tile's loads now; write after barrier
        const int kvn = kv0 + 32;
        kreg[0] = *(const u32x4*)(qkv + (size_t)(kvn + kv0c) * QKVDIM + k_off + seg0 * 8);
        kreg[1] = *(const u32x4*)(qkv + (size_t)(kvn + kv1c) * QKVDIM + k_off + seg1 * 8);
        vreg[0] = *(const u32x4*)(vTh + (size_t)dV * SEQ + kvn + q8V);
        vreg[1] = *(const u32x4*)(vTh + (size_t)(dV + 128) * SEQ + kvn + q8V);
      }

      if (kv0 <= qrow + 15) {
        f32x4 s0 = {}, s1 = {};
        __builtin_amdgcn_s_setprio(1);
#pragma unroll
        for (int cc = 0; cc < 8; ++cc) {
          const int d = cc * 32 + g * 8;
          short8 kf0 = *(const short8*)&Kl[(c * 256 + d) ^ ((c & 7) << 3)];
          s0 = __builtin_amdgcn_mfma_f32_16x16x32_bf16(qf[cc], kf0, s0, 0, 0, 0);
          short8 kf1 = *(const short8*)&Kl[((16 + c) * 256 + d) ^ ((c & 7) << 3)];
          s1 = __builtin_amdgcn_mfma_f32_16x16x32_bf16(qf[cc], kf1, s1, 0, 0, 0);
        }
        __builtin_amdgcn_s_setprio(0);

        const bool domask = (kv0 + 31 > qrow);
        float sv0[4], sv1[4];
#pragma unroll
        for (int r = 0; r < 4; ++r) {
          sv0[r] = s0[r] * SCALE;
          sv1[r] = s1[r] * SCALE;
          if (domask) {
            const int qg = qrow + g * 4 + r;
            if (kv0 + c > qg) sv0[r] = -3.0e38f;
            if (kv0 + 16 + c > qg) sv1[r] = -3.0e38f;
          }
        }
        float tm[4];
#pragma unroll
        for (int r = 0; r < 4; ++r) {
          float v = fmaxf(sv0[r], sv1[r]);
#pragma unroll
          for (int off = 1; off < 16; off <<= 1) v = fmaxf(v, __shfl_xor(v, off));
          tm[r] = v;
        }
        float need = tm[0] - mrow[0];
#pragma unroll
        for (int r = 1; r < 4; ++r) need = fmaxf(need, tm[r] - mrow[r]);
        const bool doresc = !__all(need <= 8.0f);
        float corr[4] = {1.0f, 1.0f, 1.0f, 1.0f};
        if (doresc) {
#pragma unroll
          for (int r = 0; r < 4; ++r) {
            const float mnew = fmaxf(mrow[r], tm[r]);
            corr[r] = __expf(mrow[r] - mnew);
            mrow[r] = mnew;
          }
#pragma unroll
          for (int dt = 0; dt < 16; ++dt)
#pragma unroll
            for (int r = 0; r < 4; ++r) o[dt][r] *= corr[r];
        }
#pragma unroll
        for (int r = 0; r < 4; ++r) {
          const float p0 = __expf(sv0[r] - mrow[r]);
          const float p1 = __expf(sv1[r] - mrow[r]);
          Pl[w][(g * 4 + r) * 40 + c] = f2bf(p0);
          Pl[w][(g * 4 + r) * 40 + 16 + c] = f2bf(p1);
          float rs = p0 + p1;
#pragma unroll
          for (int off = 1; off < 16; off <<= 1) rs += __shfl_xor(rs, off);
          lrow[r] = lrow[r] * corr[r] + rs;
        }

        asm volatile("s_waitcnt lgkmcnt(0)" ::: "memory");
        __builtin_amdgcn_sched_barrier(0);

        const short8 pa = *(const short8*)&Pl[w][c * 40 + g * 8];
        __builtin_amdgcn_s_setprio(1);
#pragma unroll
        for (int dt = 0; dt < 16; ++dt) {
          const short8 bv = *(const short8*)&Vl[(dt * 16 + c) * 40 + g * 8];
          o[dt] = __builtin_amdgcn_mfma_f32_16x16x32_bf16(pa, bv, o[dt], 0, 0, 0);
        }
        __builtin_amdgcn_s_setprio(0);
      }

      __syncthreads();  // all reads of tile ti done
      if (more) {
        *(u32x4*)&Kl[t * 8] = kreg[0];
        *(u32x4*)&Kl[(512 + t) * 8] = kreg[1];
        *(u32x4*)&Vl[dV * 40 + q8V] = vreg[0];
        *(u32x4*)&Vl[(dV + 128) * 40 + q8V] = vreg[1];
      }
    }

    float inv[4];
#pragma unroll
    for (int r = 0; r < 4; ++r) inv[r] = 1.0f / lrow[r];
#pragma unroll
    for (int dt = 0; dt < 16; ++dt)
#pragma unroll
      for (int r = 0; r < 4; ++r) {
        const int row = qrow + g * 4 + r;
        attnout[(size_t)row * HID + head * 256 + dt * 16 + c] = f2bf(o[dt][r] * inv[r]);
      }
  }
}

// ---------------------------------------------------------------------------
extern "C" void kernel_launch(void* const* d_in, const int* in_sizes, int n_in,
                              void* d_out, int out_size, void* d_ws, size_t ws_size,
                              hipStream_t stream) {
  const float* hidden = (const float*)d_in[0];
  const int* positions = (const int*)d_in[1];
  const float* w_qkv = (const float*)d_in[2];
  const float* w_out = (const float*)d_in[3];
  float* out = (float*)d_out;

  u16* qkv = (u16*)d_ws;                            // 48 MiB
  u16* attn = qkv + (size_t)SEQ * QKVDIM;           // 16 MiB
  u16* vT = attn + (size_t)SEQ * HID;               // 16 MiB
  u16* hid_bf = vT + (size_t)HID * SEQ;             // 16 MiB
  u16* wqkv_bf = hid_bf + (size_t)SEQ * HID;        // 96 MiB
  u16* wout_bf = wqkv_bf + (size_t)QKVDIM * HID;    // 32 MiB

  conv_kernel<<<2048, 256, 0, stream>>>(hidden, hid_bf, SEQ * HID / 8);
  conv_kernel<<<2048, 256, 0, stream>>>(w_qkv, wqkv_bf, QKVDIM * HID / 8);
  conv_kernel<<<2048, 256, 0, stream>>>(w_out, wout_bf, HID * HID / 8);
  // 1a) q/k tiles of QKV -> qkv (bf16): 256 blocks, 256x256
  gemm_pipe<1, 256><<<dim3(32, SEQ / 256), 512, 0, stream>>>(
      hid_bf, wqkv_bf, qkv, HID, HID, HID, QKVDIM);
  // 1b) v tiles, swapped-mfma -> vT (bf16, transposed): 256 blocks, 256x128
  gemm_pipe<2, 128><<<dim3(32, SEQ / 256), 512, 0, stream>>>(
      hid_bf, wqkv_bf, vT, HID, HID, HID, SEQ);
  rope_kernel<<<(SEQ * 512) / 256, 256, 0, stream>>>(qkv, positions);
  // 3) attention: 8 folded pairs x 16 heads = 128 blocks (each q-block once)
  attn_kernel<<<dim3(8, 16), 512, 0, stream>>>(qkv, vT, attn);
  // 4) out = attn * w_out^T (fp32): 256 blocks, 256x128
  gemm_pipe<0, 128><<<dim3(32, SEQ / 256), 512, 0, stream>>>(
      attn, wout_bf, out, HID, HID, HID, HID);
}

// Round 10
// 505.484 us; speedup vs baseline: 1.1084x; 1.1084x over previous
//
#include <hip/hip_runtime.h>

#define HID 4096
#define QKVDIM 12288
#define SEQ 2048
#define SCALE 0.0625f

typedef unsigned short u16;
typedef unsigned int u32;
typedef __attribute__((ext_vector_type(8))) short short8;   // 8 x bf16 (4 VGPR)
typedef __attribute__((ext_vector_type(4))) float f32x4;
typedef __attribute__((ext_vector_type(4))) unsigned int u32x4;
typedef __attribute__((ext_vector_type(4))) float float4v;

__device__ __forceinline__ u16 f2bf(float f) {
  union { float f; u32 u; } v; v.f = f;
  return (u16)((v.u + 0x7fffu + ((v.u >> 16) & 1u)) >> 16);  // RNE
}
__device__ __forceinline__ float bf2f(u16 h) {
  union { u32 u; float f; } v; v.u = ((u32)h) << 16;
  return v.f;
}
__device__ __forceinline__ u32 pk2(float a, float b) {
  return (u32)f2bf(a) | ((u32)f2bf(b) << 16);
}

// ---------------------------------------------------------------------------
// fp32 -> bf16 bulk convert (8 elems/thread, grid-stride)
// ---------------------------------------------------------------------------
__global__ __launch_bounds__(256)
void conv_kernel(const float* __restrict__ in, u16* __restrict__ out, int n8) {
  for (int i = blockIdx.x * 256 + threadIdx.x; i < n8; i += gridDim.x * 256) {
    const float* p = in + (size_t)i * 8;
    float4v f0 = *(const float4v*)p;
    float4v f1 = *(const float4v*)(p + 4);
    u32x4 pk = (u32x4){pk2(f0.x, f0.y), pk2(f0.z, f0.w), pk2(f1.x, f1.y), pk2(f1.z, f1.w)};
    *(u32x4*)(out + (size_t)i * 8) = pk;
  }
}

// ---------------------------------------------------------------------------
// PIPELINED GEMM (T3+T4, round-7 proven): 256 x BROWS tile, BK=64, 8 waves,
// ring of 4 K-half slots per matrix. BROWS = 256 or 128.
// CMODE: 0 = fp32 C; 1 = bf16 C into qkv q/k tiles; 2 = bf16 C^T into vT.
// ---------------------------------------------------------------------------
template <int CMODE, int BROWS>
__global__ __launch_bounds__(512)
void gemm_pipe(const u16* __restrict__ A, const u16* __restrict__ B,
               void* __restrict__ Cv, int K, int lda, int ldb, int ldc) {
  constexpr int NI = BROWS / 64;   // B sub-tiles per wave (4 or 2)
  constexpr int BI = BROWS / 128;  // B stage iterations (2 or 1)
  __shared__ __align__(16) u16 Asl[4][256 * 32];
  __shared__ __align__(16) u16 Bsl[4][BROWS * 32];
  const int t = threadIdx.x;  // 0..511
  const int w = t >> 6, lane = t & 63, g = lane >> 4, c = lane & 15;
  const int wm = w >> 2, wn = w & 3;

  // T1 XCD-aware swizzle (nwg % 8 == 0 in all launches)
  const int gx = gridDim.x;
  const int nwg = gx * gridDim.y;
  const int orig = blockIdx.y * gx + blockIdx.x;
  const int swz = (orig & 7) * (nwg >> 3) + (orig >> 3);
  const int bx = swz % gx, by = swz / gx;

  const int m0 = by * 256;
  int n0, vrow0 = 0;
  if (CMODE == 0) {
    n0 = bx * BROWS;
  } else if (CMODE == 1) {  // q/k tiles (BROWS=256): bx 0..31
    const int mp = bx >> 2, rr = bx & 3;
    n0 = mp * 1536 + (rr < 2 ? rr * 256 : 1024 + (rr - 2) * 256);
  } else {                  // v tiles (BROWS=128): bx 0..31
    const int mp = bx >> 2, rr = bx & 3;
    n0 = mp * 1536 + 512 + rr * 128;
    vrow0 = mp * 512 + rr * 128;
  }

  const int rowL = t >> 2;
  const int cSrc = ((t & 3) ^ ((t >> 2) & 3)) * 8;
  const u16* Asrc = A + (size_t)(m0 + rowL) * lda + cSrc;
  const u16* Bsrc = B + (size_t)(n0 + rowL) * ldb + cSrc;

  f32x4 acc[8][NI] = {};

#define STAGEH(slot, kcol)                                                     \
  {                                                                            \
    _Pragma("unroll") for (int i = 0; i < 2; ++i)                              \
        __builtin_amdgcn_global_load_lds(                                      \
            (const __attribute__((address_space(1))) u32*)(Asrc + (kcol) +     \
                                                           (size_t)(i * 128) * lda), \
            (__attribute__((address_space(3))) u32*)&Asl[slot][(i * 512 + w * 64) * 8], \
            16, 0, 0);                                                         \
    _Pragma("unroll") for (int i = 0; i < BI; ++i)                             \
        __builtin_amdgcn_global_load_lds(                                      \
            (const __attribute__((address_space(1))) u32*)(Bsrc + (kcol) +     \
                                                           (size_t)(i * 128) * ldb), \
            (__attribute__((address_space(3))) u32*)&Bsl[slot][(i * 512 + w * 64) * 8], \
            16, 0, 0);                                                         \
  }

  // prologue: Kh0(0), Kh1(0), Kh0(1)
  STAGEH(0, 0)
  STAGEH(1, 32)
  STAGEH(2, 64)

  const int NT = K >> 6;
  for (int j = 0; j < NT; ++j) {
    const int s0 = (2 * j) & 3;
#pragma unroll
    for (int h = 0; h < 2; ++h) {
      if (j + 1 < NT) {
        if (BROWS == 256)
          asm volatile("s_waitcnt vmcnt(8)\ns_barrier" ::: "memory");
        else
          asm volatile("s_waitcnt vmcnt(6)\ns_barrier" ::: "memory");
      } else if (h == 0) {
        if (BROWS == 256)
          asm volatile("s_waitcnt vmcnt(4)\ns_barrier" ::: "memory");
        else
          asm volatile("s_waitcnt vmcnt(3)\ns_barrier" ::: "memory");
      } else {
        asm volatile("s_waitcnt vmcnt(0)\ns_barrier" ::: "memory");
      }

      const u16* As = &Asl[(s0 + h) & 3][0];
      const u16* Bs = &Bsl[(s0 + h) & 3][0];
      short8 af[8], bf[NI];
#pragma unroll
      for (int mi = 0; mi < 8; ++mi) {
        const int row = wm * 128 + mi * 16 + c;
        af[mi] = *(const short8*)&As[(row * 32 + g * 8) ^ ((c & 3) << 3)];
      }
#pragma unroll
      for (int ni = 0; ni < NI; ++ni) {
        const int row = wn * (BROWS / 4) + ni * 16 + c;
        bf[ni] = *(const short8*)&Bs[(row * 32 + g * 8) ^ ((c & 3) << 3)];
      }
      if (h == 0) {
        if (j + 1 < NT) STAGEH((s0 + 3) & 3, (j + 1) * 64 + 32)
      } else {
        if (j + 2 < NT) STAGEH(s0, (j + 2) * 64)
      }

      asm volatile("s_waitcnt lgkmcnt(0)" ::: "memory");
      __builtin_amdgcn_sched_barrier(0);  // rule 18
      __builtin_amdgcn_s_setprio(1);
#pragma unroll
      for (int mi = 0; mi < 8; ++mi)
#pragma unroll
        for (int ni = 0; ni < NI; ++ni)
          acc[mi][ni] = (CMODE == 2)
              ? __builtin_amdgcn_mfma_f32_16x16x32_bf16(bf[ni], af[mi], acc[mi][ni], 0, 0, 0)
              : __builtin_amdgcn_mfma_f32_16x16x32_bf16(af[mi], bf[ni], acc[mi][ni], 0, 0, 0);
      __builtin_amdgcn_s_setprio(0);
      __builtin_amdgcn_sched_barrier(0);  // pin MFMA inside the phase
    }
  }
#undef STAGEH

  // epilogue. C/D layout: col = lane&15, row = (lane>>4)*4 + reg  [m89/m91]
#pragma unroll
  for (int mi = 0; mi < 8; ++mi)
#pragma unroll
    for (int ni = 0; ni < NI; ++ni)
#pragma unroll
      for (int r = 0; r < 4; ++r) {
        if (CMODE == 2) {
          const int vr = vrow0 + wn * (BROWS / 4) + ni * 16 + g * 4 + r;
          const int sc = m0 + wm * 128 + mi * 16 + c;
          ((u16*)Cv)[(size_t)vr * ldc + sc] = f2bf(acc[mi][ni][r]);
        } else {
          const int row = m0 + wm * 128 + mi * 16 + g * 4 + r;
          const int col = n0 + wn * (BROWS / 4) + ni * 16 + c;
          if (CMODE == 1)
            ((u16*)Cv)[(size_t)row * ldc + col] = f2bf(acc[mi][ni][r]);
          else
            ((float*)Cv)[(size_t)row * ldc + col] = acc[mi][ni][r];
        }
      }
}

// ---------------------------------------------------------------------------
// RoPE (GPT-J interleaved) in-place on q and k sections of qkv (bf16).
// ---------------------------------------------------------------------------
__global__ __launch_bounds__(256)
void rope_kernel(u16* __restrict__ qkv, const int* __restrict__ pos32) {
  const int idx = blockIdx.x * 256 + threadIdx.x;
  const int s = idx >> 9;
  const int rem = idx & 511;
  const int h = rem >> 5, i = rem & 31;
  const bool is64 = (pos32[1] == 0);
  const int pv = is64 ? pos32[2 * s] : pos32[s];
  const float pos = (float)pv;
  const float inv_freq = expf(-(float)i * (9.210340371976184f / 32.0f));
  const float f = pos * inv_freq;
  const float cs = cosf(f), sn = sinf(f);
  u16* p = qkv + (size_t)s * QKVDIM + (h >> 1) * 1536 + (h & 1) * 256 + 2 * i;
  {
    float x1 = bf2f(p[0]), x2 = bf2f(p[1]);
    p[0] = f2bf(x1 * cs - x2 * sn);
    p[1] = f2bf(x2 * cs + x1 * sn);
  }
  {
    u16* pk_ = p + 1024;
    float x1 = bf2f(pk_[0]), x2 = bf2f(pk_[1]);
    pk_[0] = f2bf(x1 * cs - x2 * sn);
    pk_[1] = f2bf(x2 * cs + x1 * sn);
  }
}

// ---------------------------------------------------------------------------
// Flash attention, causal, SPLIT-KV. Grid (16, 16) = 256 blocks (full chip).
// Block bx runs two tasks:
//   taskA: qb = bx,    half 0: KV tiles [0, 2qb+2)
//   taskB: qb = 15-bx, half 1: KV tiles [2qb+2, 4qb+4)
// -> uniform 34 stages/block. Each task stores NORMALIZED partial o/l (bf16)
// + per-row (m, l) fp32; combine_kernel merges the two halves.
// o1 -> attn buffer; o2 -> dead v-slots of qkv; ml -> dead hid_bf.
// T14 async-stage, T13 defer-rescale (THR=8), T5 setprio.
// ---------------------------------------------------------------------------
__global__ __launch_bounds__(512)
void attn_kernel(u16* __restrict__ qkv, const u16* __restrict__ vT,
                 u16* __restrict__ o1buf, float2* __restrict__ ml) {
  __shared__ u16 Kl[32 * 256];
  __shared__ u16 Vl[256 * 40];
  __shared__ u16 Pl[8][16 * 40];

  const int t = threadIdx.x;                 // 0..511
  const int w = t >> 6, lane = t & 63, g = lane >> 4, c = lane & 15;
  const int head = blockIdx.y;
  const int q_off = (head >> 1) * 1536 + (head & 1) * 256;
  const int v_off = q_off + 512;
  const int k_off = q_off + 1024;
  const u16* vTh = vT + (size_t)(head * 256) * SEQ;

  // staging maps: 1024 16B-chunks per matrix, 2 per thread (i = 0,1)
  const int kv0c = t >> 5, kv1c = (512 + t) >> 5;
  const int seg0 = (t & 31) ^ (kv0c & 7);
  const int seg1 = (t & 31) ^ (kv1c & 7);
  const int dV = t >> 2, q8V = (t & 3) * 8;

  for (int task = 0; task < 2; ++task) {
    const int qb = task ? (15 - (int)blockIdx.x) : (int)blockIdx.x;
    const int ti0 = task ? (2 * qb + 2) : 0;
    const int tiE = ti0 + 2 * qb + 2;
    const int qrow = qb * 128 + w * 16;

    short8 qf[8];
    {
      const u16* qbp = qkv + (size_t)(qrow + c) * QKVDIM + q_off + g * 8;
#pragma unroll
      for (int cc = 0; cc < 8; ++cc) qf[cc] = *(const short8*)(qbp + cc * 32);
    }

    f32x4 o[16] = {};
    float mrow[4], lrow[4];
#pragma unroll
    for (int r = 0; r < 4; ++r) { mrow[r] = -3.0e38f; lrow[r] = 0.0f; }

    u32x4 kreg[2], vreg[2];
    const int kvP = ti0 * 32;
    kreg[0] = *(const u32x4*)(qkv + (size_t)(kvP + kv0c) * QKVDIM + k_off + seg0 * 8);
    kreg[1] = *(const u32x4*)(qkv + (size_t)(kvP + kv1c) * QKVDIM + k_off + seg1 * 8);
    vreg[0] = *(const u32x4*)(vTh + (size_t)dV * SEQ + kvP + q8V);
    vreg[1] = *(const u32x4*)(vTh + (size_t)(dV + 128) * SEQ + kvP + q8V);
    __syncthreads();  // previous task readers done before overwrite
    *(u32x4*)&Kl[t * 8] = kreg[0];
    *(u32x4*)&Kl[(512 + t) * 8] = kreg[1];
    *(u32x4*)&Vl[dV * 40 + q8V] = vreg[0];
    *(u32x4*)&Vl[(dV + 128) * 40 + q8V] = vreg[1];

    for (int ti = ti0; ti < tiE; ++ti) {
      __syncthreads();  // staged tile ti visible
      const int kv0 = ti * 32;
      const bool more = (ti + 1 < tiE);
      if (more) {  // T14: issue next tile's loads now; write after barrier
        const int kvn = kv0 + 32;
        kreg[0] = *(const u32x4*)(qkv + (size_t)(kvn + kv0c) * QKVDIM + k_off + seg0 * 8);
        kreg[1] = *(const u32x4*)(qkv + (size_t)(kvn + kv1c) * QKVDIM + k_off + seg1 * 8);
        vreg[0] = *(const u32x4*)(vTh + (size_t)dV * SEQ + kvn + q8V);
        vreg[1] = *(const u32x4*)(vTh + (size_t)(dV + 128) * SEQ + kvn + q8V);
      }

      if (kv0 <= qrow + 15) {
        f32x4 s0 = {}, s1 = {};
        __builtin_amdgcn_s_setprio(1);
#pragma unroll
        for (int cc = 0; cc < 8; ++cc) {
          const int d = cc * 32 + g * 8;
          short8 kf0 = *(const short8*)&Kl[(c * 256 + d) ^ ((c & 7) << 3)];
          s0 = __builtin_amdgcn_mfma_f32_16x16x32_bf16(qf[cc], kf0, s0, 0, 0, 0);
          short8 kf1 = *(const short8*)&Kl[((16 + c) * 256 + d) ^ ((c & 7) << 3)];
          s1 = __builtin_amdgcn_mfma_f32_16x16x32_bf16(qf[cc], kf1, s1, 0, 0, 0);
        }
        __builtin_amdgcn_s_setprio(0);

        const bool domask = (kv0 + 31 > qrow);
        float sv0[4], sv1[4];
#pragma unroll
        for (int r = 0; r < 4; ++r) {
          sv0[r] = s0[r] * SCALE;
          sv1[r] = s1[r] * SCALE;
          if (domask) {
            const int qg = qrow + g * 4 + r;
            if (kv0 + c > qg) sv0[r] = -3.0e38f;
            if (kv0 + 16 + c > qg) sv1[r] = -3.0e38f;
          }
        }
        float tm[4];
#pragma unroll
        for (int r = 0; r < 4; ++r) {
          float v = fmaxf(sv0[r], sv1[r]);
#pragma unroll
          for (int off = 1; off < 16; off <<= 1) v = fmaxf(v, __shfl_xor(v, off));
          tm[r] = v;
        }
        float need = tm[0] - mrow[0];
#pragma unroll
        for (int r = 1; r < 4; ++r) need = fmaxf(need, tm[r] - mrow[r]);
        const bool doresc = !__all(need <= 8.0f);
        float corr[4] = {1.0f, 1.0f, 1.0f, 1.0f};
        if (doresc) {
#pragma unroll
          for (int r = 0; r < 4; ++r) {
            const float mnew = fmaxf(mrow[r], tm[r]);
            corr[r] = __expf(mrow[r] - mnew);
            mrow[r] = mnew;
          }
#pragma unroll
          for (int dt = 0; dt < 16; ++dt)
#pragma unroll
            for (int r = 0; r < 4; ++r) o[dt][r] *= corr[r];
        }
#pragma unroll
        for (int r = 0; r < 4; ++r) {
          const float p0 = __expf(sv0[r] - mrow[r]);
          const float p1 = __expf(sv1[r] - mrow[r]);
          Pl[w][(g * 4 + r) * 40 + c] = f2bf(p0);
          Pl[w][(g * 4 + r) * 40 + 16 + c] = f2bf(p1);
          float rs = p0 + p1;
#pragma unroll
          for (int off = 1; off < 16; off <<= 1) rs += __shfl_xor(rs, off);
          lrow[r] = lrow[r] * corr[r] + rs;
        }

        asm volatile("s_waitcnt lgkmcnt(0)" ::: "memory");
        __builtin_amdgcn_sched_barrier(0);

        const short8 pa = *(const short8*)&Pl[w][c * 40 + g * 8];
        __builtin_amdgcn_s_setprio(1);
#pragma unroll
        for (int dt = 0; dt < 16; ++dt) {
          const short8 bv = *(const short8*)&Vl[(dt * 16 + c) * 40 + g * 8];
          o[dt] = __builtin_amdgcn_mfma_f32_16x16x32_bf16(pa, bv, o[dt], 0, 0, 0);
        }
        __builtin_amdgcn_s_setprio(0);
      }

      __syncthreads();  // all reads of tile ti done
      if (more) {
        *(u32x4*)&Kl[t * 8] = kreg[0];
        *(u32x4*)&Kl[(512 + t) * 8] = kreg[1];
        *(u32x4*)&Vl[dV * 40 + q8V] = vreg[0];
        *(u32x4*)&Vl[(dV + 128) * 40 + q8V] = vreg[1];
      }
    }

    // epilogue: store normalized partial (bf16) + (m, l) per row
    float inv[4];
#pragma unroll
    for (int r = 0; r < 4; ++r) inv[r] = lrow[r] > 0.0f ? 1.0f / lrow[r] : 0.0f;
#pragma unroll
    for (int dt = 0; dt < 16; ++dt)
#pragma unroll
      for (int r = 0; r < 4; ++r) {
        const int row = qrow + g * 4 + r;
        const u16 val = f2bf(o[dt][r] * inv[r]);
        if (task == 0)
          o1buf[(size_t)row * HID + head * 256 + dt * 16 + c] = val;
        else
          qkv[(size_t)row * QKVDIM + v_off + dt * 16 + c] = val;
      }
    if (c == 0) {
#pragma unroll
      for (int r = 0; r < 4; ++r) {
        const int row = qrow + g * 4 + r;
        ml[(task * 16 + head) * SEQ + row] = float2{mrow[r], lrow[r]};
      }
    }
  }
}

// ---------------------------------------------------------------------------
// Combine the two KV-half partials: attn = (o1*w1 + o2*w2)/(w1+w2),
// w_i = l_i * exp(m_i - max(m1,m2)). o2 lives in the qkv v-slots.
// ---------------------------------------------------------------------------
__global__ __launch_bounds__(256)
void combine_kernel(u16* __restrict__ attnb, const u16* __restrict__ qkv,
                    const float2* __restrict__ ml) {
  const int idx = blockIdx.x * 256 + threadIdx.x;  // SEQ*HID/8 tasks
  const int row = idx >> 9;
  const int ch = idx & 511;
  const int head = ch >> 5;
  const int d8 = (ch & 31) * 8;
  const float2 ml1 = ml[head * SEQ + row];
  const float2 ml2 = ml[(16 + head) * SEQ + row];
  const float m = fmaxf(ml1.x, ml2.x);
  float w1 = ml1.y * __expf(ml1.x - m);
  float w2 = ml2.y * __expf(ml2.x - m);
  const float inv = 1.0f / (w1 + w2);
  w1 *= inv;
  w2 *= inv;
  u16* p1 = attnb + (size_t)row * HID + head * 256 + d8;
  const u16* p2 = qkv + (size_t)row * QKVDIM + (head >> 1) * 1536 + 512 +
                  (head & 1) * 256 + d8;
  u32x4 a = *(const u32x4*)p1;
  u32x4 b = *(const u32x4*)p2;
  const u16* ap = (const u16*)&a;
  const u16* bp = (const u16*)&b;
  u32x4 outv;
#pragma unroll
  for (int j = 0; j < 4; ++j) {
    const float lo = bf2f(ap[2 * j]) * w1 + bf2f(bp[2 * j]) * w2;
    const float hi = bf2f(ap[2 * j + 1]) * w1 + bf2f(bp[2 * j + 1]) * w2;
    outv[j] = pk2(lo, hi);
  }
  *(u32x4*)p1 = outv;
}

// ---------------------------------------------------------------------------
extern "C" void kernel_launch(void* const* d_in, const int* in_sizes, int n_in,
                              void* d_out, int out_size, void* d_ws, size_t ws_size,
                              hipStream_t stream) {
  const float* hidden = (const float*)d_in[0];
  const int* positions = (const int*)d_in[1];
  const float* w_qkv = (const float*)d_in[2];
  const float* w_out = (const float*)d_in[3];
  float* out = (float*)d_out;

  u16* qkv = (u16*)d_ws;                            // 48 MiB
  u16* attn = qkv + (size_t)SEQ * QKVDIM;           // 16 MiB (o1 partial)
  u16* vT = attn + (size_t)SEQ * HID;               // 16 MiB
  u16* hid_bf = vT + (size_t)HID * SEQ;             // 16 MiB (ml after gemms)
  u16* wqkv_bf = hid_bf + (size_t)SEQ * HID;        // 96 MiB
  u16* wout_bf = wqkv_bf + (size_t)QKVDIM * HID;    // 32 MiB
  float2* ml = (float2*)hid_bf;                     // 512 KiB, dead region

  conv_kernel<<<2048, 256, 0, stream>>>(hidden, hid_bf, SEQ * HID / 8);
  conv_kernel<<<2048, 256, 0, stream>>>(w_qkv, wqkv_bf, QKVDIM * HID / 8);
  conv_kernel<<<2048, 256, 0, stream>>>(w_out, wout_bf, HID * HID / 8);
  // 1a) q/k tiles of QKV -> qkv (bf16): 256 blocks, 256x256
  gemm_pipe<1, 256><<<dim3(32, SEQ / 256), 512, 0, stream>>>(
      hid_bf, wqkv_bf, qkv, HID, HID, HID, QKVDIM);
  // 1b) v tiles, swapped-mfma -> vT (bf16, transposed): 256 blocks, 256x128
  gemm_pipe<2, 128><<<dim3(32, SEQ / 256), 512, 0, stream>>>(
      hid_bf, wqkv_bf, vT, HID, HID, HID, SEQ);
  rope_kernel<<<(SEQ * 512) / 256, 256, 0, stream>>>(qkv, positions);
  // 3) split-KV attention: 16 task-pairs x 16 heads = 256 blocks, 34 stages
  attn_kernel<<<dim3(16, 16), 512, 0, stream>>>(qkv, vT, attn, ml);
  combine_kernel<<<SEQ * HID / 8 / 256, 256, 0, stream>>>(attn, qkv, ml);
  // 4) out = attn * w_out^T (fp32): 256 blocks, 256x128
  gemm_pipe<0, 128><<<dim3(32, SEQ / 256), 512, 0, stream>>>(
      attn, wout_bf, out, HID, HID, HID, HID);
}